// Round 1
// 38637.354 us; speedup vs baseline: 1.0144x; 1.0144x over previous
//
#include <hip/hip_runtime.h>

#define T_STEPS 32768
#define OUT_BASE 9830400  // 32768*300

typedef _Float16 h2 __attribute__((ext_vector_type(2)));

__device__ __forceinline__ float fdot2(h2 a, h2 b, float c) {
#if __has_builtin(__builtin_amdgcn_fdot2)
    return __builtin_amdgcn_fdot2(a, b, c, false);
#else
    return c + (float)a.x * (float)b.x + (float)a.y * (float)b.y;
#endif
}

__device__ __forceinline__ float sigf(float x) { return 1.f / (1.f + __expf(-x)); }

__device__ __forceinline__ float tanh_f(float x) {
    float a = fabsf(x);
    float e = __expf(-2.f * a);
    float t = (1.f - e) / (1.f + e);
    return x < 0.f ? -t : t;
}

// quad_perm DPP cross-lane read (VALU speed, no LDS). CTRL: 0xB1=xor1, 0x4E=xor2, 0x1B=xor3.
template <int CTRL>
__device__ __forceinline__ float qperm(float x) {
#if __has_builtin(__builtin_amdgcn_update_dpp)
    return __builtin_bit_cast(
        float, __builtin_amdgcn_update_dpp(0, __builtin_bit_cast(int, x), CTRL, 0xF, 0xF, true));
#else
    return __shfl_xor(x, CTRL == 0xB1 ? 1 : (CTRL == 0x4E ? 2 : 3));
#endif
}

// Barrier that drains ONLY LDS (lgkmcnt). __syncthreads() would emit
// s_waitcnt vmcnt(0) before s_barrier, serializing the x0p prefetch /
// h1s store latency into every tick.
__device__ __forceinline__ void bar_lds() {
    asm volatile("s_waitcnt lgkmcnt(0)\n\ts_barrier" ::: "memory");
}

// ---------------- A0: Wc = W_ih_l0 @ W_inp  [400x300]; bc = W_ih_l0@b_inp + b_ih0 + b_hh0 ----------------
__global__ void k_precomp(const float* __restrict__ W_inp, const float* __restrict__ b_inp,
                          const float* __restrict__ W_ih0, const float* __restrict__ b_ih0,
                          const float* __restrict__ b_hh0,
                          float* __restrict__ Wc, float* __restrict__ bc) {
    int idx = blockIdx.x * 256 + threadIdx.x;
    if (idx < 120000) {
        int r = idx / 300, d = idx % 300;
        float acc = 0.f;
        for (int h = 0; h < 100; h++) acc += W_ih0[r * 100 + h] * W_inp[h * 300 + d];
        Wc[idx] = acc;
    } else if (idx < 120400) {
        int r = idx - 120000;
        float acc = b_ih0[r] + b_hh0[r];
        for (int h = 0; h < 100; h++) acc += W_ih0[r * 100 + h] * b_inp[h];
        bc[r] = acc;
    }
}

// ---------------- A1: x0p[t][perm(r)] = inputs[t] . Wc[r] + bc[r], stored f16 ----------------
// perm(r) = (r%100)*4 + r/100 so that k_scan thread j (gate g=j&3, unit u=j>>2,
// row r = g*100+u) reads x0p[t*400 + j] with unit stride.
__global__ __launch_bounds__(512) void k_xproj(const float* __restrict__ inp,
                                               const float* __restrict__ Wc,
                                               const float* __restrict__ bc,
                                               _Float16* __restrict__ x0p) {
    __shared__ float xs[32 * 300];
    int t0 = blockIdx.x * 32;
    for (int idx = threadIdx.x; idx < 9600; idx += 512) xs[idx] = inp[(size_t)t0 * 300 + idx];
    __syncthreads();
    int j = threadIdx.x;
    if (j < 400) {
        float acc[32];
#pragma unroll
        for (int i = 0; i < 32; i++) acc[i] = 0.f;
        const float4* w4 = (const float4*)(Wc + j * 300);
        const float4* x4 = (const float4*)xs;
        for (int d4 = 0; d4 < 75; d4++) {
            float4 w = w4[d4];
#pragma unroll
            for (int ti = 0; ti < 32; ti++) {
                float4 x = x4[ti * 75 + d4];
                acc[ti] += w.x * x.x + w.y * x.y + w.z * x.z + w.w * x.w;
            }
        }
        float bb = bc[j];
        int dst = (j % 100) * 4 + j / 100;
#pragma unroll
        for (int ti = 0; ti < 32; ti++)
            x0p[(size_t)(t0 + ti) * 400 + dst] = (_Float16)(acc[ti] + bb);
    }
}

// One tick, quad-per-unit layout. Thread j: gate g=j&3 of unit u=j>>2 for BOTH
// layers (row r = g*100+u). Gates never touch LDS: each lane applies its own
// nonlinearity (tanh = 2*sigmoid(2x)-1, branchless via s_/addc_), lane 0 of the
// quad gathers the other three gates via quad_perm DPP and does the c/h update
// for layer 0 (tick T_) and layer 1 (tick T_-1, software-pipelined). h values
// are written straight into the double-buffered hbuf as f16 (ds_write_b16) --
// no pair-packing shuffle. ONE barrier per tick (read hbuf[P_], write hbuf[1-P_]).
#define TICK(T_, XREG_, TNEXT_, P_) do {                                                     \
    if (j < 400) {                                                                           \
        float xc_ = XREG_;                                                                   \
        int tn_ = (TNEXT_) < T_STEPS ? (TNEXT_) : T_STEPS - 1;                               \
        XREG_ = (float)x0p[(size_t)tn_ * 400 + j];                                           \
        const float4* h4_ = (const float4*)hbuf[P_];                                         \
        float a0a_ = xc_, a0b_ = 0.f;                                                        \
        float a1a_ = b1c, a1b_ = 0.f, a1c_ = 0.f, a1d_ = 0.f;                                \
        _Pragma("unroll")                                                                    \
        for (int c_ = 0; c_ < 12; c_++) {                                                    \
            float4 v_ = h4_[c_];                                                             \
            h2 hx_ = __builtin_bit_cast(h2, v_.x), hy_ = __builtin_bit_cast(h2, v_.y);       \
            h2 hz_ = __builtin_bit_cast(h2, v_.z), hw_ = __builtin_bit_cast(h2, v_.w);       \
            a0a_ = fdot2(w0[4 * c_ + 0], hx_, a0a_);                                         \
            a0b_ = fdot2(w0[4 * c_ + 1], hy_, a0b_);                                         \
            a0a_ = fdot2(w0[4 * c_ + 2], hz_, a0a_);                                         \
            a0b_ = fdot2(w0[4 * c_ + 3], hw_, a0b_);                                         \
            a1a_ = fdot2(w1[4 * c_ + 0], hx_, a1a_);                                         \
            a1b_ = fdot2(w1[4 * c_ + 1], hy_, a1b_);                                         \
            a1c_ = fdot2(w1[4 * c_ + 2], hz_, a1c_);                                         \
            a1d_ = fdot2(w1[4 * c_ + 3], hw_, a1d_);                                         \
        }                                                                                    \
        {                                                                                    \
            float4 v_ = h4_[12];                                                             \
            h2 hx_ = __builtin_bit_cast(h2, v_.x), hy_ = __builtin_bit_cast(h2, v_.y);       \
            h2 hz_ = __builtin_bit_cast(h2, v_.z), hw_ = __builtin_bit_cast(h2, v_.w);       \
            a0a_ = fdot2(w0[48], hx_, a0a_);                                                 \
            a0b_ = fdot2(w0[49], hy_, a0b_);                                                 \
            a1a_ = fdot2(w1[48], hx_, a1a_);                                                 \
            a1b_ = fdot2(w1[49], hy_, a1b_);                                                 \
            a1c_ = fdot2(w1[50], hz_, a1c_);                                                 \
            a1d_ = fdot2(w1[51], hw_, a1d_);                                                 \
        }                                                                                    \
        _Pragma("unroll")                                                                    \
        for (int c_ = 13; c_ < 25; c_++) {                                                   \
            float4 v_ = h4_[c_];                                                             \
            a1a_ = fdot2(w1[4 * c_ + 0], __builtin_bit_cast(h2, v_.x), a1a_);                \
            a1b_ = fdot2(w1[4 * c_ + 1], __builtin_bit_cast(h2, v_.y), a1b_);                \
            a1c_ = fdot2(w1[4 * c_ + 2], __builtin_bit_cast(h2, v_.z), a1c_);                \
            a1d_ = fdot2(w1[4 * c_ + 3], __builtin_bit_cast(h2, v_.w), a1d_);                \
        }                                                                                    \
        float acc0_ = a0a_ + a0b_;                                                           \
        float acc1_ = (a1a_ + a1b_) + (a1c_ + a1d_);                                         \
        float nl0_ = __builtin_fmaf(sigf(acc0_ * s_), s_, addc_);                            \
        float nl1_ = __builtin_fmaf(sigf(acc1_ * s_), s_, addc_);                            \
        float f0_ = qperm<0xB1>(nl0_), g0_ = qperm<0x4E>(nl0_), o0_ = qperm<0x1B>(nl0_);     \
        float f1_ = qperm<0xB1>(nl1_), g1_ = qperm<0x4E>(nl1_), o1_ = qperm<0x1B>(nl1_);     \
        if ((j & 3) == 0) {                                                                  \
            int u_ = j >> 2;                                                                 \
            c0 = f0_ * c0 + nl0_ * g0_;                                                      \
            float h0v_ = o0_ * tanh_f(c0);                                                   \
            hbuf[1 - (P_)][u_] = (_Float16)h0v_;                                             \
            if ((T_) >= 1) {                                                                 \
                c1 = f1_ * c1 + nl1_ * g1_;                                                  \
                float h1v_ = o1_ * tanh_f(c1);                                               \
                hbuf[1 - (P_)][100 + u_] = (_Float16)h1v_;                                   \
                h1s[(size_t)((T_) - 1) * 100 + u_] = h1v_;                                   \
            }                                                                                \
            if ((T_) == T_STEPS - 1) { outTail[u_] = h0v_; outTail[200 + u_] = c0; }         \
        }                                                                                    \
    }                                                                                        \
    bar_lds();                                                                               \
} while (0)

// ---------------- Scan: single block, 448 threads (400 active), layer1 lags 1 tick ----------------
// amdgpu_waves_per_eu(2,2): 256-VGPR budget so the 150 packed-f16 weight regs
// stay in arch VGPRs.
__global__ __launch_bounds__(448) __attribute__((amdgpu_waves_per_eu(2, 2)))
void k_scan(const _Float16* __restrict__ x0p,
            const float* __restrict__ Whh0,
            const float* __restrict__ Wih1,
            const float* __restrict__ Whh1,
            const float* __restrict__ bih1,
            const float* __restrict__ bhh1,
            float* __restrict__ h1s,
            float* __restrict__ outTail) {
    // double-buffered f16 hidden state: [b][0..99]=h0, [b][100..199]=h1
    __shared__ __align__(16) _Float16 hbuf[2][200];
    const int j = threadIdx.x;

    h2 w0[50];   // W_hh_l0 row r (packed f16)
    h2 w1[100];  // [W_ih_l1 row r | W_hh_l1 row r]
    float b1c = 0.f, xa = 0.f, xb = 0.f;
    if (j < 400) {
        int r = (j & 3) * 100 + (j >> 2);  // gate-major row for quad-per-unit layout
        const float2* p0 = (const float2*)(Whh0 + r * 100);
#pragma unroll
        for (int k = 0; k < 50; k++) { float2 v = p0[k]; h2 q; q.x = (_Float16)v.x; q.y = (_Float16)v.y; w0[k] = q; }
        const float2* p1 = (const float2*)(Wih1 + r * 100);
#pragma unroll
        for (int k = 0; k < 50; k++) { float2 v = p1[k]; h2 q; q.x = (_Float16)v.x; q.y = (_Float16)v.y; w1[k] = q; }
        const float2* p2 = (const float2*)(Whh1 + r * 100);
#pragma unroll
        for (int k = 0; k < 50; k++) { float2 v = p2[k]; h2 q; q.x = (_Float16)v.x; q.y = (_Float16)v.y; w1[50 + k] = q; }
        b1c = bih1[r] + bhh1[r];
        xa = (float)x0p[j];        // x(0), permuted layout
        xb = (float)x0p[400 + j];  // x(1)
    }
    if (j < 200) ((unsigned int*)hbuf)[j] = 0u;  // zero both buffers (800 B)
    // branchless gate nonlinearity constants: lane g==2 computes tanh = 2*sig(2x)-1
    const float s_ = ((j & 3) == 2) ? 2.f : 1.f;
    const float addc_ = ((j & 3) == 2) ? -1.f : 0.f;
    float c0 = 0.f, c1 = 0.f;
    __syncthreads();

    for (int t = 0; t < T_STEPS; t += 2) {
        TICK(t, xa, t + 2, 0);      // read hbuf[0], write hbuf[1]; prefetch x(t+2)
        TICK(t + 1, xb, t + 3, 1);  // read hbuf[1], write hbuf[0]; prefetch x(t+3)
    }

    // Drain tick (t == T_STEPS): gates1 for step T-1 from hbuf[0] = {h0(T-1), h1(T-2)}.
    if (j < 400) {
        const float4* h4 = (const float4*)hbuf[0];
        float a1a = b1c, a1b = 0.f, a1c = 0.f, a1d = 0.f;
#pragma unroll
        for (int c = 0; c < 25; c++) {
            float4 v = h4[c];
            a1a = fdot2(w1[4 * c + 0], __builtin_bit_cast(h2, v.x), a1a);
            a1b = fdot2(w1[4 * c + 1], __builtin_bit_cast(h2, v.y), a1b);
            a1c = fdot2(w1[4 * c + 2], __builtin_bit_cast(h2, v.z), a1c);
            a1d = fdot2(w1[4 * c + 3], __builtin_bit_cast(h2, v.w), a1d);
        }
        float acc1 = (a1a + a1b) + (a1c + a1d);
        float nl1 = __builtin_fmaf(sigf(acc1 * s_), s_, addc_);
        float f1 = qperm<0xB1>(nl1), g1 = qperm<0x4E>(nl1), o1 = qperm<0x1B>(nl1);
        if ((j & 3) == 0) {
            int u = j >> 2;
            c1 = f1 * c1 + nl1 * g1;
            float h1v = o1 * tanh_f(c1);
            h1s[(size_t)(T_STEPS - 1) * 100 + u] = h1v;
            outTail[100 + u] = h1v;
            outTail[300 + u] = c1;
        }
    }
}

// ---------------- C: outputs[t][d] = h1s[t] . W_out[d] + b_out[d] ----------------
__global__ __launch_bounds__(320) void k_out(const float* __restrict__ h1s,
                                             const float* __restrict__ Wout,
                                             const float* __restrict__ bout,
                                             float* __restrict__ out) {
    __shared__ float hs[32 * 100];
    int t0 = blockIdx.x * 32;
    for (int idx = threadIdx.x; idx < 3200; idx += 320) hs[idx] = h1s[(size_t)t0 * 100 + idx];
    __syncthreads();
    int d = threadIdx.x;
    if (d < 300) {
        float acc[32];
#pragma unroll
        for (int i = 0; i < 32; i++) acc[i] = 0.f;
        const float4* w4 = (const float4*)(Wout + d * 100);
        const float4* h4 = (const float4*)hs;
        for (int j4 = 0; j4 < 25; j4++) {
            float4 w = w4[j4];
#pragma unroll
            for (int ti = 0; ti < 32; ti++) {
                float4 h = h4[ti * 25 + j4];
                acc[ti] += w.x * h.x + w.y * h.y + w.z * h.z + w.w * h.w;
            }
        }
        float bb = bout[d];
#pragma unroll
        for (int ti = 0; ti < 32; ti++) out[(size_t)(t0 + ti) * 300 + d] = acc[ti] + bb;
    }
}

extern "C" void kernel_launch(void* const* d_in, const int* in_sizes, int n_in,
                              void* d_out, int out_size, void* d_ws, size_t ws_size,
                              hipStream_t stream) {
    const float* inputs = (const float*)d_in[0];
    const float* W_inp  = (const float*)d_in[1];
    const float* b_inp  = (const float*)d_in[2];
    const float* W_ih0  = (const float*)d_in[3];
    const float* W_hh0  = (const float*)d_in[4];
    const float* b_ih0  = (const float*)d_in[5];
    const float* b_hh0  = (const float*)d_in[6];
    const float* W_ih1  = (const float*)d_in[7];
    const float* W_hh1  = (const float*)d_in[8];
    const float* b_ih1  = (const float*)d_in[9];
    const float* b_hh1  = (const float*)d_in[10];
    const float* W_out  = (const float*)d_in[11];
    const float* b_out  = (const float*)d_in[12];
    float* out = (float*)d_out;

    char* ws = (char*)d_ws;
    _Float16* x0p = (_Float16*)ws;                         // 32768*400*2 = 26,214,400 B
    float* h1s = (float*)(ws + 26214400);                  // 32768*100*4 = 13,107,200 B
    float* Wc  = (float*)(ws + 26214400 + 13107200);       // 400*300*4   =    480,000 B
    float* bc  = Wc + 120000;                              // 400*4 B

    k_precomp<<<471, 256, 0, stream>>>(W_inp, b_inp, W_ih0, b_ih0, b_hh0, Wc, bc);
    k_xproj<<<1024, 512, 0, stream>>>(inputs, Wc, bc, x0p);
    k_scan<<<1, 448, 0, stream>>>(x0p, W_hh0, W_ih1, W_hh1, b_ih1, b_hh1, h1s, out + OUT_BASE);
    k_out<<<1024, 320, 0, stream>>>(h1s, W_out, b_out, out);
}